// Round 11
// baseline (174.511 us; speedup 1.0000x reference)
//
#include <hip/hip_runtime.h>
#include <hip/hip_bf16.h>

#define TEMP_INV (1.0f / 0.07f)
#define LOG2E 1.4426950408889634f
#define LN2 0.6931471805599453f
#define CFIX 21.0f

typedef __attribute__((ext_vector_type(4))) float f32x4;
typedef __attribute__((ext_vector_type(8))) short bf16x8;

__device__ __forceinline__ ushort f2bf(float x) {
  union { float f; unsigned u; } v; v.f = x;
  unsigned r = (v.u + 0x7fffu + ((v.u >> 16) & 1u)) >> 16;
  return (ushort)r;
}

__device__ __forceinline__ void gload16(const ushort* g, ushort* l) {
  __builtin_amdgcn_global_load_lds(
      (const __attribute__((address_space(1))) void*)g,
      (__attribute__((address_space(3))) void*)l, 16, 0, 0);
}

// ---------------- Kernel 1: L2-normalize rows -> bf16 feats, cross dot, ------
// ---------------- and zero the lsum accumulator (folded) ---------------------
__global__ __launch_bounds__(256) void norm_kernel(
    const float* __restrict__ A, const float* __restrict__ P,
    ushort* __restrict__ F, float* __restrict__ cross,
    float* __restrict__ lsum, int B, int D) {
  const int row = blockIdx.x;
  const int t = threadIdx.x;
  {
    const int zi = row * 256 + t;
    if (zi < 2 * B) lsum[zi] = 0.f;
  }
  const float4* a4 = reinterpret_cast<const float4*>(A + (size_t)row * D);
  const float4* p4 = reinterpret_cast<const float4*>(P + (size_t)row * D);
  const int n4 = D >> 2;
  float sa = 0.f, sp = 0.f, sx = 0.f;
  for (int i = t; i < n4; i += 256) {
    float4 av = a4[i], pv = p4[i];
    sa += av.x * av.x + av.y * av.y + av.z * av.z + av.w * av.w;
    sp += pv.x * pv.x + pv.y * pv.y + pv.z * pv.z + pv.w * pv.w;
    sx += av.x * pv.x + av.y * pv.y + av.z * pv.z + av.w * pv.w;
  }
#pragma unroll
  for (int off = 32; off; off >>= 1) {
    sa += __shfl_down(sa, off);
    sp += __shfl_down(sp, off);
    sx += __shfl_down(sx, off);
  }
  __shared__ float red[3][4];
  const int wid = t >> 6, lane = t & 63;
  if (lane == 0) { red[0][wid] = sa; red[1][wid] = sp; red[2][wid] = sx; }
  __syncthreads();
  sa = red[0][0] + red[0][1] + red[0][2] + red[0][3];
  sp = red[1][0] + red[1][1] + red[1][2] + red[1][3];
  sx = red[2][0] + red[2][1] + red[2][2] + red[2][3];
  const float ia = rsqrtf(sa), ip = rsqrtf(sp);
  ushort* fa = F + (size_t)row * D;
  ushort* fp = F + (size_t)(B + row) * D;
  for (int i = t; i < n4; i += 256) {
    float4 av = a4[i], pv = p4[i];
    ushort4 oa, op;
    oa.x = f2bf(av.x * ia); oa.y = f2bf(av.y * ia);
    oa.z = f2bf(av.z * ia); oa.w = f2bf(av.w * ia);
    op.x = f2bf(pv.x * ip); op.y = f2bf(pv.y * ip);
    op.z = f2bf(pv.z * ip); op.w = f2bf(pv.w * ip);
    reinterpret_cast<ushort4*>(fa)[i] = oa;
    reinterpret_cast<ushort4*>(fp)[i] = op;
  }
  if (t == 0) cross[row] = sx * ia * ip;
}

// ---------------- Kernel 2: half-tile triangular fused Gram ------------------
// Work unit = 128 j-rows x 256 i-rows x FULL K (j-split of a 256^2 triangle
// tile; legal since row-sums over disjoint j-sets commute — K-split is NOT).
// 1056 units over 512 persistent blocks (all co-resident: 48KB LDS -> up to
// 3 blocks/CU; 8 waves, acc[4][4]=64 VGPR, bounds (512,2) — R9 lesson).
// Inner loop = R9's proven drain-loop {vmcnt(0); barrier; read frags;
// stage(v+1) GUARDED (no tail clamp: a stale clamped write would race the
// next unit's prologue write to the same bytes); MFMA}.
// LDS per buf: A 8KB (128x32) at 0, B 16KB (256x32) at 8192B. Region layout
// verified 0-conflict R2-R10: (trow,k): lrow=trow>>1; slot=(trow&1)*4+(k>>3);
// byte=lrow*128+((slot^(lrow&7))<<4)+(k&7)*2. Staged linear, source carries
// the inverse swizzle.
#define VT 32  /* K-32 steps: D/32 */

__global__ __launch_bounds__(512, 2) void gram_lse_kernel(
    const ushort* __restrict__ F, float* __restrict__ lsum, int NN, int D) {
  __shared__ ushort lds[2][12288];  // [buf][A 4096 | B 8192 ushorts] = 48 KB
  const int nrb = NN >> 8;
  const int ntri = nrb * (nrb + 1) / 2;
  const int nunits = 2 * ntri;  // 1056
  const int nblk = gridDim.x;
  const int base = nunits / nblk, rem = nunits - base * nblk;
  const int bid = blockIdx.x;
  const int nMine = base + (bid < rem ? 1 : 0);
  const int sMine = bid * base + (bid < rem ? bid : rem);

  const int t = threadIdx.x;
  const int lane = t & 63, w = t >> 6;
  const int lo = lane & 15, hi = lane >> 4;
  const int wr = w >> 2, wn = w & 3;  // wr: j-64 half of 128; wn: i-64 of 256

  // staging decode (verified algebra): chunk c -> lrow=c>>3, sc=c&7,
  // cu=sc^(lrow&7), trow=lrow*2+(cu>>2), kc=cu&3
  const int c0i = w * 64 + lane;            // A chunk / B chunk 0 (0..511)
  const int c1i = (w + 8) * 64 + lane;      // B chunk 1 (512..1023)
  const int lr0 = c0i >> 3, cu0 = (c0i & 7) ^ (lr0 & 7);
  const int trow0 = lr0 * 2 + (cu0 >> 2), kc0 = cu0 & 3;
  const int lr1 = c1i >> 3, cu1 = (c1i & 7) ^ (lr1 & 7);
  const int trow1 = lr1 * 2 + (cu1 >> 2), kc1 = cu1 & 3;
  const int dA = w * 512;                   // ushort offsets (wave-uniform)
  const int dB0 = 4096 + w * 512;
  const int dB1 = 4096 + (w + 8) * 512;

  // fragment read base (bytes within a region) — verified 0-conflict
  const int cA = (((lo & 1) << 2) | hi) ^ (lo >> 1);
  const int rdBase = (lo >> 1) * 128 + cA * 16;

  const float scl = LOG2E * TEMP_INV;

  for (int ui = 0; ui < nMine; ++ui) {
    const int u = sMine + ui;
    const int lin = u >> 1, h = u & 1;
    int by = (int)((sqrtf(8.f * (float)lin + 1.f) - 1.f) * 0.5f);
    while ((by + 1) * (by + 2) / 2 <= lin) ++by;
    while (by * (by + 1) / 2 > lin) --by;
    const int bx = lin - by * (by + 1) / 2;  // bx <= by
    const int r0 = bx * 256;                 // i rows (B operand, N side)
    const int c0h = by * 256 + h * 128;      // j rows (A operand, M side)
    const bool diag = (bx == by);

    const ushort* sA = F + (size_t)(c0h + trow0) * D + kc0 * 8;
    const ushort* sB0 = F + (size_t)(r0 + trow0) * D + kc0 * 8;
    const ushort* sB1 = F + (size_t)(r0 + trow1) * D + kc1 * 8;

#define STAGE(V, BUF)                                   \
  do {                                                  \
    const int o_ = (V) * 32;                            \
    gload16(sA + o_, &lds[BUF][dA]);                    \
    gload16(sB0 + o_, &lds[BUF][dB0]);                  \
    gload16(sB1 + o_, &lds[BUF][dB1]);                  \
  } while (0)

    f32x4 acc[4][4];
#pragma unroll
    for (int a = 0; a < 4; ++a)
#pragma unroll
      for (int b = 0; b < 4; ++b) acc[a][b] = (f32x4){0.f, 0.f, 0.f, 0.f};

    STAGE(0, 0);  // prologue

    for (int v = 0; v < VT; ++v) {
      const int buf = v & 1;
      asm volatile("s_waitcnt vmcnt(0)" ::: "memory");
      __builtin_amdgcn_s_barrier();
      asm volatile("" ::: "memory");

      const char* L = (const char*)&lds[buf][0];
      bf16x8 af[4], bfr[4];
#pragma unroll
      for (int m = 0; m < 4; ++m)
        af[m] = *(const bf16x8*)(L + wr * 4096 + m * 1024 + rdBase);
#pragma unroll
      for (int n = 0; n < 4; ++n)
        bfr[n] = *(const bf16x8*)(L + 8192 + wn * 4096 + n * 1024 + rdBase);

      if (v + 1 < VT) STAGE(v + 1, buf ^ 1);  // guarded (no tail clamp)

      __builtin_amdgcn_s_setprio(1);
#pragma unroll
      for (int m = 0; m < 4; ++m)
#pragma unroll
        for (int n = 0; n < 4; ++n)
          acc[m][n] = __builtin_amdgcn_mfma_f32_16x16x32_bf16(
              af[m], bfr[n], acc[m][n], 0, 0, 0);
      __builtin_amdgcn_s_setprio(0);
      asm volatile("" ::: "memory");
    }

    // ---- dual-side epilogue (R6 mapping, halved) ----
    // acc[m][n][rg]: j = c0h + wr*64 + m*16 + hi*4 + rg
    //               i = r0  + wn*64 + n*16 + lo
    float s_i[4] = {0.f, 0.f, 0.f, 0.f};
    float s_j[16];
#pragma unroll
    for (int q = 0; q < 16; ++q) s_j[q] = 0.f;
    {
      const int dgb = (r0 + wn * 64) - (c0h + wr * 64);
#pragma unroll
      for (int n = 0; n < 4; ++n) {
        const int dg = dgb + n * 16 + lo;
#pragma unroll
        for (int m = 0; m < 4; ++m)
#pragma unroll
          for (int rg = 0; rg < 4; ++rg) {
            const int jloc = m * 16 + hi * 4 + rg;
            float e = exp2f(acc[m][n][rg] * scl - CFIX);
            if (diag && dg == jloc) e = 0.f;
            s_i[n] += e;
            s_j[m * 4 + rg] += e;
          }
      }
    }
    // i-side: reduce over hi groups (wave's 64 j), add to rows i
#pragma unroll
    for (int n = 0; n < 4; ++n) {
      float v = s_i[n];
      v += __shfl_xor(v, 16);
      v += __shfl_xor(v, 32);
      if (hi == 0) atomicAdd(&lsum[r0 + wn * 64 + n * 16 + lo], v);
    }
    // j-side: reduce over lo lanes (wave's 64 i), add to rows j
    if (!diag) {
#pragma unroll
      for (int q = 0; q < 16; ++q) {
        float v = s_j[q];
        v += __shfl_xor(v, 1);
        v += __shfl_xor(v, 2);
        v += __shfl_xor(v, 4);
        v += __shfl_xor(v, 8);
        if (lo == 0)
          atomicAdd(&lsum[c0h + wr * 64 + (q >> 2) * 16 + hi * 4 + (q & 3)],
                    v);
      }
    }
#undef STAGE
  }

  asm volatile("s_waitcnt vmcnt(0)" ::: "memory");
}

// ---------------- Kernel 3a: per-row loss -> per-block partial sums ----------
__global__ __launch_bounds__(256) void finalize_part(
    const float* __restrict__ lsum, const float* __restrict__ cross,
    const int* __restrict__ labels, float* __restrict__ bsum,
    float* __restrict__ bcnt, int B) {
  const int NN = 2 * B;
  const int i = blockIdx.x * 256 + threadIdx.x;
  float sum = 0.f, cnt = 0.f;
  if (i < NN) {
    const float lse = LN2 * (CFIX + log2f(lsum[i]));
    const float lab = (float)labels[i % B];
    sum = (lse - cross[i % B] * TEMP_INV) * lab;
    cnt = lab;
  }
#pragma unroll
  for (int off = 32; off; off >>= 1) {
    sum += __shfl_down(sum, off);
    cnt += __shfl_down(cnt, off);
  }
  __shared__ float rs[4], rc[4];
  const int wid = threadIdx.x >> 6, lane = threadIdx.x & 63;
  if (lane == 0) { rs[wid] = sum; rc[wid] = cnt; }
  __syncthreads();
  if (threadIdx.x == 0) {
    bsum[blockIdx.x] = rs[0] + rs[1] + rs[2] + rs[3];
    bcnt[blockIdx.x] = rc[0] + rc[1] + rc[2] + rc[3];
  }
}

// ---------------- Kernel 3b: final reduce ------------------------------------
__global__ __launch_bounds__(64) void finalize_final(
    const float* __restrict__ bsum, const float* __restrict__ bcnt,
    float* __restrict__ out, int nb) {
  const int t = threadIdx.x;
  float s = (t < nb) ? bsum[t] : 0.f;
  float c = (t < nb) ? bcnt[t] : 0.f;
#pragma unroll
  for (int off = 32; off; off >>= 1) {
    s += __shfl_down(s, off);
    c += __shfl_down(c, off);
  }
  if (t == 0) out[0] = (c > 0.f) ? s / c : 0.f;
}

extern "C" void kernel_launch(void* const* d_in, const int* in_sizes, int n_in,
                              void* d_out, int out_size, void* d_ws, size_t ws_size,
                              hipStream_t stream) {
  const float* A = (const float*)d_in[0];
  const float* P = (const float*)d_in[1];
  const int* labels = (const int*)d_in[2];
  float* out = (float*)d_out;
  const int B = in_sizes[2];
  const int D = in_sizes[0] / B;
  const int NN = 2 * B;

  char* ws = (char*)d_ws;
  ushort* F = (ushort*)ws;
  size_t off = (size_t)NN * D * sizeof(ushort);
  off = (off + 255) & ~(size_t)255;
  float* cross = (float*)(ws + off);
  off += (size_t)B * sizeof(float);
  off = (off + 255) & ~(size_t)255;
  float* lsum = (float*)(ws + off);
  off += (size_t)NN * sizeof(float);
  off = (off + 255) & ~(size_t)255;
  float* bsum = (float*)(ws + off);
  off += 64 * sizeof(float);
  float* bcnt = (float*)(ws + off);

  norm_kernel<<<B, 256, 0, stream>>>(A, P, F, cross, lsum, B, D);
  const int nrb = NN >> 8;               // 32 row-panels of 256
  const int ntri = nrb * (nrb + 1) / 2;  // 528 tiles -> 1056 half-tile units
  const int nunits = 2 * ntri;
  const int nblk = (nunits < 512) ? nunits : 512;
  gram_lse_kernel<<<nblk, 512, 0, stream>>>(F, lsum, NN, D);
  const int nb = (NN + 255) / 256;  // 32
  finalize_part<<<nb, 256, 0, stream>>>(lsum, cross, labels, bsum, bcnt, B);
  finalize_final<<<1, 64, 0, stream>>>(bsum, bcnt, out, nb);
}

// Round 12
// 115.416 us; speedup vs baseline: 1.5120x; 1.5120x over previous
//
#include <hip/hip_runtime.h>
#include <hip/hip_bf16.h>

#define TEMP_INV (1.0f / 0.07f)
#define LOG2E 1.4426950408889634f
#define LN2 0.6931471805599453f
#define CFIX 21.0f

typedef __attribute__((ext_vector_type(4))) float f32x4;

__device__ __forceinline__ void gload16(const unsigned char* g,
                                        unsigned char* l) {
  __builtin_amdgcn_global_load_lds(
      (const __attribute__((address_space(1))) void*)g,
      (__attribute__((address_space(3))) void*)l, 16, 0, 0);
}

// ---------------- Kernel 1: L2-normalize -> fp8(e4m3) feats x16, cross, ------
// ---------------- and zero lsum (folded) -------------------------------------
__global__ __launch_bounds__(256) void norm_kernel(
    const float* __restrict__ A, const float* __restrict__ P,
    unsigned char* __restrict__ F, float* __restrict__ cross,
    float* __restrict__ lsum, int B, int D) {
  const int row = blockIdx.x;
  const int t = threadIdx.x;
  {
    const int zi = row * 256 + t;
    if (zi < 2 * B) lsum[zi] = 0.f;
  }
  const float4* a4 = reinterpret_cast<const float4*>(A + (size_t)row * D);
  const float4* p4 = reinterpret_cast<const float4*>(P + (size_t)row * D);
  const int n4 = D >> 2;
  float sa = 0.f, sp = 0.f, sx = 0.f;
  for (int i = t; i < n4; i += 256) {
    float4 av = a4[i], pv = p4[i];
    sa += av.x * av.x + av.y * av.y + av.z * av.z + av.w * av.w;
    sp += pv.x * pv.x + pv.y * pv.y + pv.z * pv.z + pv.w * pv.w;
    sx += av.x * pv.x + av.y * pv.y + av.z * pv.z + av.w * pv.w;
  }
#pragma unroll
  for (int off = 32; off; off >>= 1) {
    sa += __shfl_down(sa, off);
    sp += __shfl_down(sp, off);
    sx += __shfl_down(sx, off);
  }
  __shared__ float red[3][4];
  const int wid = t >> 6, lane = t & 63;
  if (lane == 0) { red[0][wid] = sa; red[1][wid] = sp; red[2][wid] = sx; }
  __syncthreads();
  sa = red[0][0] + red[0][1] + red[0][2] + red[0][3];
  sp = red[1][0] + red[1][1] + red[1][2] + red[1][3];
  sx = red[2][0] + red[2][1] + red[2][2] + red[2][3];
  const float ian = rsqrtf(sa), ipn = rsqrtf(sp);
  const float ia = ian * 16.f, ip = ipn * 16.f;  // x16 -> e4m3 range
  unsigned char* fa = F + (size_t)row * D;
  unsigned char* fp = F + (size_t)(B + row) * D;
  for (int i = t; i < n4; i += 256) {
    float4 av = a4[i], pv = p4[i];
    int qa = 0, qp = 0;
    qa = __builtin_amdgcn_cvt_pk_fp8_f32(av.x * ia, av.y * ia, qa, false);
    qa = __builtin_amdgcn_cvt_pk_fp8_f32(av.z * ia, av.w * ia, qa, true);
    qp = __builtin_amdgcn_cvt_pk_fp8_f32(pv.x * ip, pv.y * ip, qp, false);
    qp = __builtin_amdgcn_cvt_pk_fp8_f32(pv.z * ip, pv.w * ip, qp, true);
    reinterpret_cast<int*>(fa)[i] = qa;
    reinterpret_cast<int*>(fp)[i] = qp;
  }
  if (t == 0) cross[row] = sx * ian * ipn;
}

// ---------------- Kernel 2: triangular fused Gram (fp8, 4-deep pipeline) -----
// 256x256 triangle tiles, FULL K=1024, 8 waves (2x4), 16x16x32 fp8 MFMA
// (= bf16 rate, half the bytes). 176 blocks x exactly 3 tiles (528=176*3,
// no stragglers). LDS = 4 tile-buffers x (A,B) x (k0,k1) x 8KB = 128KB ->
// tiles t+1..t+3 in flight (~12 loads/thread-group) => HBM/L3 latency hidden
// (R10/R11 lesson: Little's law capped effective BW at 1.3 TB/s).
// Schedule per K-64 iter t: {vmcnt(8); barrier; [KS0: read frags, stage
// A/B(t+3,k0), 32 MFMA]; [KS1: same with k1]}. Writes of tile t+3 vs reads of
// tile t: 3-buffer separation; buffer (t+3)&3 last read at iter t-1, consumed
// before this iter's barrier. Tail: clamped dummy stages keep vmcnt count
// uniform (R8/R11 class of bug). Inter-tile: vmcnt(0)+barrier.
// fp8 region (256 trows x 32 k = 8KB): lrow=trow>>2 (128B bank period);
// cu=(trow&3)*2+(k>=16); chunk=cu^(lrow&7); byte=lrow*128+chunk*16+(k&15).
// Staged linear (chunk c = thread id), source carries inverse swizzle.
#define VT 16  /* K-64 tiles: D/64 */

__global__ __launch_bounds__(512, 2) void gram_lse_kernel(
    const unsigned char* __restrict__ F, float* __restrict__ lsum, int NN,
    int D) {
  __shared__ unsigned char lds8[4][2][2][8192];  // [buf][A/B][khalf][8KB]
  const int nrb = NN >> 8;
  const int ntri = nrb * (nrb + 1) / 2;
  int b = blockIdx.x;
  b = (b & 7) * (gridDim.x >> 3) + (b >> 3);  // XCD swizzle (176 = 8*22)
  const int lin0 = b * 3;

  const int t = threadIdx.x;
  const int lane = t & 63, w = t >> 6;
  const int lo = lane & 15, hi = lane >> 4;
  const int wr = w >> 2, wn = w & 3;  // wr: j-half(128), wn: i-quarter(64)

  // staging decode: chunk c = tid; lrow=c>>3; cu=(c&7)^(lrow&7);
  // trow=lrow*4+(cu>>1); kc=(cu&1)*16
  const int ci = t;
  const int lrS = ci >> 3, cuS = (ci & 7) ^ (lrS & 7);
  const int trowS = lrS * 4 + (cuS >> 1), kcS = (cuS & 1) << 4;
  const int dstW = w * 1024;  // wave-uniform byte base in 8KB region

  // fragment read byte offsets (region-relative, tile-independent)
  // r row, k-half hi: lrow=r>>2; cu=((r&3)<<1)|(hi>>1);
  // byte = lrow*128 + ((cu^(lrow&7))<<4) + (hi&1)*8
  int offA[8], offB[4];
#pragma unroll
  for (int mf = 0; mf < 8; ++mf) {
    const int r = wr * 128 + mf * 16 + lo;
    const int lr = r >> 2;
    const int cu = ((r & 3) << 1) | (hi >> 1);
    offA[mf] = lr * 128 + ((cu ^ (lr & 7)) << 4) + ((hi & 1) << 3);
  }
#pragma unroll
  for (int nf = 0; nf < 4; ++nf) {
    const int r = wn * 64 + nf * 16 + lo;
    const int lr = r >> 2;
    const int cu = ((r & 3) << 1) | (hi >> 1);
    offB[nf] = lr * 128 + ((cu ^ (lr & 7)) << 4) + ((hi & 1) << 3);
  }

  const float scl = LOG2E * TEMP_INV / 256.f;  // descale x16*x16

  for (int ti = 0; ti < 3; ++ti) {
    const int lin = lin0 + ti;
    int by = (int)((sqrtf(8.f * (float)lin + 1.f) - 1.f) * 0.5f);
    while ((by + 1) * (by + 2) / 2 <= lin) ++by;
    while (by * (by + 1) / 2 > lin) --by;
    const int bx = lin - by * (by + 1) / 2;  // bx <= by
    const int r0 = bx * 256;  // i rows (B operand, N side)
    const int c0 = by * 256;  // j rows (A operand, M side)
    const bool diag = (bx == by);

    const unsigned char* srcA = F + (size_t)(c0 + trowS) * D + kcS;
    const unsigned char* srcB = F + (size_t)(r0 + trowS) * D + kcS;

    // STAGE one 8KB region (1 gload16/thread). Clamp addr, UNclamped buf.
#define STAGE_A(T, KS)                                              \
  do {                                                              \
    int v_ = (T); if (v_ > VT - 1) v_ = VT - 1;                     \
    gload16(srcA + v_ * 64 + (KS) * 32, &lds8[(T) & 3][0][KS][dstW]); \
  } while (0)
#define STAGE_B(T, KS)                                              \
  do {                                                              \
    int v_ = (T); if (v_ > VT - 1) v_ = VT - 1;                     \
    gload16(srcB + v_ * 64 + (KS) * 32, &lds8[(T) & 3][1][KS][dstW]); \
  } while (0)

    f32x4 acc[8][4];
#pragma unroll
    for (int a = 0; a < 8; ++a)
#pragma unroll
      for (int bb = 0; bb < 4; ++bb) acc[a][bb] = (f32x4){0.f, 0.f, 0.f, 0.f};

    // prologue: tiles 0,1,2 fully staged (12 loads in flight)
#pragma unroll
    for (int pt = 0; pt < 3; ++pt) {
      STAGE_A(pt, 0); STAGE_B(pt, 0);
      STAGE_A(pt, 1); STAGE_B(pt, 1);
    }

    for (int v = 0; v < VT; ++v) {
      const int buf = v & 3;
      // tiles t+1, t+2 stay in flight (8 loads); tile t drained
      asm volatile("s_waitcnt vmcnt(8)" ::: "memory");
      __builtin_amdgcn_s_barrier();
      asm volatile("" ::: "memory");

#pragma unroll
      for (int KS = 0; KS < 2; ++KS) {
        const unsigned char* RA = &lds8[buf][0][KS][0];
        const unsigned char* RB = &lds8[buf][1][KS][0];
        long aF[8], bF[4];
#pragma unroll
        for (int nf = 0; nf < 4; ++nf) bF[nf] = *(const long*)(RB + offB[nf]);
#pragma unroll
        for (int mf = 0; mf < 8; ++mf) aF[mf] = *(const long*)(RA + offA[mf]);

        if (KS == 0) { STAGE_A(v + 3, 0); STAGE_B(v + 3, 0); }
        else         { STAGE_A(v + 3, 1); STAGE_B(v + 3, 1); }

        __builtin_amdgcn_s_setprio(1);
#pragma unroll
        for (int mf = 0; mf < 8; ++mf)
#pragma unroll
          for (int nf = 0; nf < 4; ++nf)
            acc[mf][nf] = __builtin_amdgcn_mfma_f32_16x16x32_fp8_fp8(
                aF[mf], bF[nf], acc[mf][nf], 0, 0, 0);
        __builtin_amdgcn_s_setprio(0);
      }
      asm volatile("" ::: "memory");
    }

    // ---- dual-side epilogue (verbatim mapping, absmax-0 verified R6-R10) ----
    // acc[mf][nf][rg]: j = c0 + wr*128 + mf*16 + hi*4 + rg
    //                  i = r0 + wn*64 + nf*16 + lo
    float s_i[4] = {0.f, 0.f, 0.f, 0.f};
    float s_j[32];
#pragma unroll
    for (int q = 0; q < 32; ++q) s_j[q] = 0.f;
    {
      const int jb2 = c0 + wr * 128;
#pragma unroll
      for (int nf = 0; nf < 4; ++nf) {
        const int dg = (r0 + wn * 64 + nf * 16 + lo) - jb2;
#pragma unroll
        for (int mf = 0; mf < 8; ++mf)
#pragma unroll
          for (int rg = 0; rg < 4; ++rg) {
            const int jloc = mf * 16 + hi * 4 + rg;
            float e = exp2f(acc[mf][nf][rg] * scl - CFIX);
            if (diag && dg == jloc) e = 0.f;
            s_i[nf] += e;
            s_j[mf * 4 + rg] += e;
          }
      }
    }
#pragma unroll
    for (int nf = 0; nf < 4; ++nf) {
      float v = s_i[nf];
      v += __shfl_xor(v, 16);
      v += __shfl_xor(v, 32);
      if (hi == 0) atomicAdd(&lsum[r0 + wn * 64 + nf * 16 + lo], v);
    }
    if (!diag) {
#pragma unroll
      for (int q = 0; q < 32; ++q) {
        float v = s_j[q];
        v += __shfl_xor(v, 1);
        v += __shfl_xor(v, 2);
        v += __shfl_xor(v, 4);
        v += __shfl_xor(v, 8);
        if (lo == 0)
          atomicAdd(&lsum[c0 + wr * 128 + (q >> 2) * 16 + hi * 4 + (q & 3)],
                    v);
      }
    }

    // drain dummy/clamped stages before next tile's prologue overwrites
    asm volatile("s_waitcnt vmcnt(0)" ::: "memory");
    __builtin_amdgcn_s_barrier();
    asm volatile("" ::: "memory");
#undef STAGE_A
#undef STAGE_B
  }
}

// ---------------- Kernel 3a: per-row loss -> per-block partial sums ----------
__global__ __launch_bounds__(256) void finalize_part(
    const float* __restrict__ lsum, const float* __restrict__ cross,
    const int* __restrict__ labels, float* __restrict__ bsum,
    float* __restrict__ bcnt, int B) {
  const int NN = 2 * B;
  const int i = blockIdx.x * 256 + threadIdx.x;
  float sum = 0.f, cnt = 0.f;
  if (i < NN) {
    const float lse = LN2 * (CFIX + log2f(lsum[i]));
    const float lab = (float)labels[i % B];
    sum = (lse - cross[i % B] * TEMP_INV) * lab;
    cnt = lab;
  }
#pragma unroll
  for (int off = 32; off; off >>= 1) {
    sum += __shfl_down(sum, off);
    cnt += __shfl_down(cnt, off);
  }
  __shared__ float rs[4], rc[4];
  const int wid = threadIdx.x >> 6, lane = threadIdx.x & 63;
  if (lane == 0) { rs[wid] = sum; rc[wid] = cnt; }
  __syncthreads();
  if (threadIdx.x == 0) {
    bsum[blockIdx.x] = rs[0] + rs[1] + rs[2] + rs[3];
    bcnt[blockIdx.x] = rc[0] + rc[1] + rc[2] + rc[3];
  }
}

// ---------------- Kernel 3b: final reduce ------------------------------------
__global__ __launch_bounds__(64) void finalize_final(
    const float* __restrict__ bsum, const float* __restrict__ bcnt,
    float* __restrict__ out, int nb) {
  const int t = threadIdx.x;
  float s = (t < nb) ? bsum[t] : 0.f;
  float c = (t < nb) ? bcnt[t] : 0.f;
#pragma unroll
  for (int off = 32; off; off >>= 1) {
    s += __shfl_down(s, off);
    c += __shfl_down(c, off);
  }
  if (t == 0) out[0] = (c > 0.f) ? s / c : 0.f;
}

extern "C" void kernel_launch(void* const* d_in, const int* in_sizes, int n_in,
                              void* d_out, int out_size, void* d_ws, size_t ws_size,
                              hipStream_t stream) {
  const float* A = (const float*)d_in[0];
  const float* P = (const float*)d_in[1];
  const int* labels = (const int*)d_in[2];
  float* out = (float*)d_out;
  const int B = in_sizes[2];
  const int D = in_sizes[0] / B;
  const int NN = 2 * B;

  char* ws = (char*)d_ws;
  unsigned char* F = (unsigned char*)ws;
  size_t off = (size_t)NN * D;  // fp8: 1 B/elem
  off = (off + 255) & ~(size_t)255;
  float* cross = (float*)(ws + off);
  off += (size_t)B * sizeof(float);
  off = (off + 255) & ~(size_t)255;
  float* lsum = (float*)(ws + off);
  off += (size_t)NN * sizeof(float);
  off = (off + 255) & ~(size_t)255;
  float* bsum = (float*)(ws + off);
  off += 64 * sizeof(float);
  float* bcnt = (float*)(ws + off);

  norm_kernel<<<B, 256, 0, stream>>>(A, P, F, cross, lsum, B, D);
  const int nrb = NN >> 8;               // 32 row-panels of 256
  const int ntri = nrb * (nrb + 1) / 2;  // 528 = 176 * 3 exactly
  gram_lse_kernel<<<ntri / 3, 512, 0, stream>>>(F, lsum, NN, D);
  const int nb = (NN + 255) / 256;  // 32
  finalize_part<<<nb, 256, 0, stream>>>(lsum, cross, labels, bsum, bcnt, B);
  finalize_final<<<1, 64, 0, stream>>>(bsum, bcnt, out, nb);
}